// Round 11
// baseline (272.461 us; speedup 1.0000x reference)
//
#include <hip/hip_runtime.h>
#include <hip/hip_bf16.h>
#include <math.h>

#define B_ROWS 32768

typedef __attribute__((ext_vector_type(8)))  short        s8v;
typedef __attribute__((ext_vector_type(4)))  float        f4v;
typedef __attribute__((ext_vector_type(2)))  unsigned int u2v;
typedef __attribute__((ext_vector_type(4)))  unsigned int u4v;

__device__ __forceinline__ short f2bf(float f){            // f32 -> bf16 RNE
  unsigned u = __builtin_bit_cast(unsigned, f);
  u = (u + 0x7fffu + ((u >> 16) & 1u)) >> 16;
  return (short)u;
}
// packed pair convert (RNE) — builtin path (inline-asm variant NaN'd in r2/r7)
__device__ __forceinline__ unsigned cpk(float a, float b){
  __hip_bfloat16_raw lo = (__hip_bfloat16_raw)__float2bfloat16(a);
  __hip_bfloat16_raw hi = (__hip_bfloat16_raw)__float2bfloat16(b);
  return (unsigned)lo.x | ((unsigned)hi.x << 16);
}
__device__ __forceinline__ float bf_lo(unsigned u){ return __builtin_bit_cast(float, u << 16); }
__device__ __forceinline__ float bf_hi(unsigned u){ return __builtin_bit_cast(float, u & 0xffff0000u); }

#define MFMA16(A,B,C) __builtin_amdgcn_mfma_f32_16x16x32_bf16((A),(B),(C),0,0,0)

typedef __attribute__((address_space(1))) const unsigned int gu32;
typedef __attribute__((address_space(3))) unsigned int lu32;
__device__ __forceinline__ void gl_lds16(const unsigned short* g, char* l){
  __builtin_amdgcn_global_load_lds((gu32*)(const void*)g, (lu32*)(void*)l, 16, 0, 0);
}

// ---------------- LDS layout (bytes) — 81152 <= 80KiB => 2 WGs/CU ----------------
#define OXFT 0          // f32 [64 dims][68] x-state transposed
#define XFT_S 68
#define OXHB 17408      // bf16 [64 batch][40] current x-half, batch-major (xk source)
#define XHB_S 40
#define OHB  22528      // bf16 [64 batch][136] hidden chunk; also 2 reduce slots (8704B each)
#define HB_S 136
#define SL_S 68
#define SLOT_B 8704
#define OW1  39936      // 40960B single W1 chunk buffer, fragment-linear (40 tiles x 1KB)
#define OLJ  80896      // f32[64]
#define SM_SZ 81152

// ws (bf16, fragment-linear): W1 [24][4 chunks][40 tiles][512], W2 [24][64 tiles][512]
#define WF_W2 1966080
#define W_TOTAL 2752512

// -------- one-time f32 -> bf16 fragment-linear rearrangement (same layout as r10) --------
__global__ void cvtw_frag(const float* __restrict__ s1w1, const float* __restrict__ s1w2,
                          const float* __restrict__ s2w1, const float* __restrict__ s2w2,
                          unsigned short* __restrict__ dst)
{
  long t = (long)blockIdx.x * blockDim.x + threadIdx.x;
  if (t >= W_TOTAL) return;
  float v;
  if (t < WF_W2){
    int m = (int)(t / 81920); int r = (int)(t - (long)m*81920);
    int c = r / 20480;  int r2 = r - c*20480;
    int tile = r2 >> 9; int r3 = r2 & 511;
    int lane = r3 >> 3; int e = r3 & 7;
    int rg = tile / 5,  kk = tile - rg*5;
    int l15 = lane & 15, lq = lane >> 4;
    int h  = c*128 + rg*16 + l15;
    int ki = kk*32 + lq*8 + e;
    const float* src = (m & 1) ? s1w1 : s2w1;
    v = src[(size_t)(m >> 1)*81920 + h*160 + ki];
  } else {
    long u = t - WF_W2;
    int m = (int)(u / 32768); int r = (int)(u - (long)m*32768);
    int g = r >> 9; int r3 = r & 511;
    int lane = r3 >> 3; int e = r3 & 7;
    int c = g >> 4, hs = (g >> 2) & 3, ot = g & 3;   // hs = hw2*2 + kk2
    int l15 = lane & 15, lq = lane >> 4;
    int o = ot*16 + l15;
    int h = c*128 + hs*32 + lq*8 + e;
    const float* src = (m & 1) ? s1w2 : s2w2;
    v = src[(size_t)(m >> 1)*32768 + o*512 + h];
  }
  dst[t] = (unsigned short)f2bf(v);
}

__global__ __launch_bounds__(256, 2) void cinn_dma(
    const float* __restrict__ q, const float* __restrict__ Hg,
    const int* __restrict__ perms,
    const float* __restrict__ ls_g, const float* __restrict__ bi_g,
    const float* __restrict__ s1b1, const float* __restrict__ s1b2,
    const float* __restrict__ s2b1, const float* __restrict__ s2b2,
    const unsigned short* __restrict__ wbf,
    float* __restrict__ outz, float* __restrict__ outlj)
{
  __shared__ __align__(16) char sm[SM_SZ];
  const int tid = threadIdx.x;
  const int rowbase = blockIdx.x * 64;
  const int lane = tid & 63, wave = tid >> 6;
  const int hw = wave >> 1, ng = wave & 1;     // hw: hidden-half / k-split; ng: batch-half
  const int l15 = lane & 15, lq = lane >> 4;

  float* XFT = (float*)(sm + OXFT);
  short* XHB = (short*)(sm + OXHB);
  short* HB  = (short*)(sm + OHB);
  float* LOGJ= (float*)(sm + OLJ);

  // init XFT from q (coalesced read, strided LDS write, once)
  {
    int b = tid >> 2, j = tid & 3;
    const float* src = q + (size_t)(rowbase + b)*64 + j*16;
    #pragma unroll
    for (int i = 0; i < 4; ++i){
      f4v v = *(const f4v*)(src + 4*i);
      #pragma unroll
      for (int jj = 0; jj < 4; ++jj)
        XFT[(j*16 + 4*i + jj)*XFT_S + b] = v[jj];
    }
  }
  if (tid < 64) LOGJ[tid] = 0.f;
  __syncthreads();

  // H-part B-fragments: loaded ONCE, register-resident (2 nt x 4 kk)
  s8v hfr[2][4];
  #pragma unroll
  for (int nt = 0; nt < 2; ++nt){
    int b = rowbase + ng*32 + nt*16 + l15;
    #pragma unroll
    for (int kkh = 0; kkh < 4; ++kkh){
      const float* hp = Hg + (size_t)b*128 + kkh*32 + lq*8;
      f4v a = *(const f4v*)hp;
      f4v c = *(const f4v*)(hp + 4);
      u4v u = {cpk(a[0],a[1]), cpk(a[2],a[3]), cpk(c[0],c[1]), cpk(c[2],c[3])};
      hfr[nt][kkh] = __builtin_bit_cast(s8v, u);
    }
  }

  // prologue: DMA MLP0 chunk0 (drained by the m=0 permute barriers)
  {
    const unsigned short* g = wbf + wave*5120 + lane*8;
    char* lb = sm + OW1 + wave*10240;
    #pragma unroll
    for (int k = 0; k < 10; ++k) gl_lds16(g + k*512, lb + k*1024);
  }

  for (int m = 0; m < 24; ++m){
    const int bp = m & 1;
    const unsigned short* w1sec = wbf + (size_t)m*81920;
    const unsigned short* w2sec = wbf + WF_W2 + (size_t)m*32768;
    const float* b1p = (bp ? s1b1 : s2b1) + (m >> 1)*512;
    const float* b2p = (bp ? s1b2 : s2b2) + (m >> 1)*64;

    if (!bp){
      int blk = m >> 1;
      // per-thread table reads (L2-hot, wave-redundant x4 — no LDS tables)
      int   pd = perms[blk*64 + lane];
      float e  = __expf(ls_g[blk*64 + lane]);
      float bi = bi_g[blk*64 + lane];
      int bg = wave;
      f4v v[4];
      #pragma unroll
      for (int i = 0; i < 4; ++i)
        v[i] = *(const f4v*)(XFT + pd*XFT_S + bg*16 + 4*i);
      __syncthreads();
      #pragma unroll
      for (int i = 0; i < 4; ++i){
        #pragma unroll
        for (int jj = 0; jj < 4; ++jj) v[i][jj] = fmaf(v[i][jj], e, bi);
        *(f4v*)(XFT + lane*XFT_S + bg*16 + 4*i) = v[i];
      }
      if (lane >= 32){   // x2 -> XHB (even MLP's x-input)
        #pragma unroll
        for (int i = 0; i < 4; ++i)
          #pragma unroll
          for (int jj = 0; jj < 4; ++jj)
            XHB[(bg*16 + 4*i + jj)*XHB_S + (lane - 32)] = f2bf(v[i][jj]);
      }
      __syncthreads();
    }

    // xk: one b128 per nt from XHB (batch-major bf16)
    s8v xk[2];
    #pragma unroll
    for (int nt = 0; nt < 2; ++nt)
      xk[nt] = *(const s8v*)(XHB + (ng*32 + nt*16 + l15)*XHB_S + lq*8);

    f4v b2v[4];
    if (hw == 0){
      #pragma unroll
      for (int ot = 0; ot < 4; ++ot)
        b2v[ot] = *(const f4v*)(b2p + ot*16 + lq*4);
    }

    f4v racc[4][2];
    #pragma unroll
    for (int ot = 0; ot < 4; ++ot)
      #pragma unroll
      for (int nt = 0; nt < 2; ++nt)
        racc[ot][nt] = (f4v){0.f,0.f,0.f,0.f};

    #pragma unroll
    for (int c = 0; c < 4; ++c){
      // W2 A-frags for this chunk (frag-linear, coalesced), b1
      s8v w2c[2][4];
      #pragma unroll
      for (int kk2 = 0; kk2 < 2; ++kk2)
        #pragma unroll
        for (int ot = 0; ot < 4; ++ot)
          w2c[kk2][ot] = *(const s8v*)(w2sec + (size_t)((c*4 + hw*2 + kk2)*4 + ot)*512 + lane*8);
      f4v b1v[4];
      #pragma unroll
      for (int mt = 0; mt < 4; ++mt)
        b1v[mt] = *(const f4v*)(b1p + c*128 + hw*64 + mt*16 + lq*4);

      // ---- GEMM1 chunk c: hidden rows hw*64 + mt*16 (frag-linear LDS reads)
      const short* W1c = (const short*)(sm + OW1);
      f4v acc[4][2];
      #pragma unroll
      for (int mt = 0; mt < 4; ++mt)
        #pragma unroll
        for (int nt = 0; nt < 2; ++nt) acc[mt][nt] = (f4v){0.f,0.f,0.f,0.f};
      #pragma unroll
      for (int kk = 0; kk < 5; ++kk){
        s8v a[4];
        #pragma unroll
        for (int mt = 0; mt < 4; ++mt)
          a[mt] = *(const s8v*)(W1c + ((hw*4 + mt)*5 + kk)*512 + lane*8);
        #pragma unroll
        for (int nt = 0; nt < 2; ++nt){
          s8v bb = (kk == 0) ? xk[nt] : hfr[nt][kk-1];
          #pragma unroll
          for (int mt = 0; mt < 4; ++mt)
            acc[mt][nt] = MFMA16(a[mt], bb, acc[mt][nt]);
        }
      }
      // bias + relu + pack -> own HB region
      #pragma unroll
      for (int mt = 0; mt < 4; ++mt){
        f4v bv = b1v[mt];
        #pragma unroll
        for (int nt = 0; nt < 2; ++nt){
          float h0 = fmaxf(acc[mt][nt][0] + bv[0], 0.f);
          float h1 = fmaxf(acc[mt][nt][1] + bv[1], 0.f);
          float h2 = fmaxf(acc[mt][nt][2] + bv[2], 0.f);
          float h3 = fmaxf(acc[mt][nt][3] + bv[3], 0.f);
          *(u2v*)(HB + (ng*32 + nt*16 + l15)*HB_S + hw*64 + mt*16 + lq*4) = (u2v){cpk(h0,h1), cpk(h2,h3)};
        }
      }
      __syncthreads();   // A: all waves done reading W1buf for chunk c

      // DMA next chunk (c<3) or next MLP's chunk0 (c==3) — hides under GEMM2
      if (!(m == 23 && c == 3)){
        const unsigned short* gsec = (c < 3) ? w1sec : (w1sec + 81920);
        const int cn = (c < 3) ? c + 1 : 0;
        const unsigned short* g = gsec + cn*20480 + wave*5120 + lane*8;
        char* lb = sm + OW1 + wave*10240;
        #pragma unroll
        for (int k = 0; k < 10; ++k) gl_lds16(g + k*512, lb + k*1024);
      }

      // ---- GEMM2 k-slice (own 64 hidden rows, 2 kk2 sub-slices)
      #pragma unroll
      for (int kk2 = 0; kk2 < 2; ++kk2){
        #pragma unroll
        for (int nt = 0; nt < 2; ++nt){
          s8v bb = *(const s8v*)(HB + (ng*32 + nt*16 + l15)*HB_S + hw*64 + kk2*32 + lq*8);
          #pragma unroll
          for (int ot = 0; ot < 4; ++ot)
            racc[ot][nt] = MFMA16(w2c[kk2][ot], bb, racc[ot][nt]);
        }
      }
      __syncthreads();   // B: DMA drained; at c==3 also frees HB for the slots
    }

    // ---- 2 reduce slots in HB (dead), +b2 on hw0
    {
      short* SL = (short*)(sm + OHB + hw*SLOT_B);
      #pragma unroll
      for (int ot = 0; ot < 4; ++ot)
        #pragma unroll
        for (int nt = 0; nt < 2; ++nt){
          float r0 = racc[ot][nt][0], r1 = racc[ot][nt][1];
          float r2 = racc[ot][nt][2], r3 = racc[ot][nt][3];
          if (hw == 0){ r0 += b2v[ot][0]; r1 += b2v[ot][1]; r2 += b2v[ot][2]; r3 += b2v[ot][3]; }
          *(u2v*)(SL + (ng*32 + nt*16 + l15)*SL_S + ot*16 + lq*4) = (u2v){cpk(r0,r1), cpk(r2,r3)};
        }
    }
    __syncthreads();     // C: slots visible

    // ---- coupling: sum 2 slots, le = 0.636*atan(rL); y = exp(le)*x_half + rR
    {
      int b = tid & 63, og = tid >> 6;
      float le[8] = {0,0,0,0,0,0,0,0}, ra[8] = {0,0,0,0,0,0,0,0};
      #pragma unroll
      for (int ms = 0; ms < 2; ++ms){
        const short* SL = (const short*)(sm + OHB + ms*SLOT_B);
        u2v L0 = *(const u2v*)(SL + b*SL_S + og*8);
        u2v L1 = *(const u2v*)(SL + b*SL_S + og*8 + 4);
        u2v R0 = *(const u2v*)(SL + b*SL_S + 32 + og*8);
        u2v R1 = *(const u2v*)(SL + b*SL_S + 32 + og*8 + 4);
        le[0]+=bf_lo(L0[0]); le[1]+=bf_hi(L0[0]); le[2]+=bf_lo(L0[1]); le[3]+=bf_hi(L0[1]);
        le[4]+=bf_lo(L1[0]); le[5]+=bf_hi(L1[0]); le[6]+=bf_lo(L1[1]); le[7]+=bf_hi(L1[1]);
        ra[0]+=bf_lo(R0[0]); ra[1]+=bf_hi(R0[0]); ra[2]+=bf_lo(R0[1]); ra[3]+=bf_hi(R0[1]);
        ra[4]+=bf_lo(R1[0]); ra[5]+=bf_hi(R1[0]); ra[6]+=bf_lo(R1[1]); ra[7]+=bf_hi(R1[1]);
      }
      float part = 0.f, y[8];
      #pragma unroll
      for (int j = 0; j < 8; ++j){
        float l = 0.636f * atanf(le[j]);
        int d = bp*32 + og*8 + j;
        y[j] = __expf(l) * XFT[d*XFT_S + b] + ra[j];
        XFT[d*XFT_S + b] = y[j];
        part += l;
      }
      if (!bp){  // y1 feeds the odd MLP's xk
        u4v u = {cpk(y[0],y[1]), cpk(y[2],y[3]), cpk(y[4],y[5]), cpk(y[6],y[7])};
        *(u4v*)(XHB + b*XHB_S + og*8) = u;
      }
      atomicAdd(&LOGJ[b], part);
    }
    __syncthreads();     // E: coupling done (also orders next MLP's reads)
  }

  // output: transpose back, coalesced global writes
  {
    int b = tid >> 2, j = tid & 3;
    float* dst = outz + (size_t)(rowbase + b)*64 + j*16;
    #pragma unroll
    for (int i = 0; i < 4; ++i){
      f4v w;
      #pragma unroll
      for (int jj = 0; jj < 4; ++jj)
        w[jj] = XFT[(j*16 + 4*i + jj)*XFT_S + b];
      *(f4v*)(dst + 4*i) = w;
    }
  }
  if (tid < 64){
    float p = 0.f;
    #pragma unroll
    for (int k = 0; k < 12; ++k) p += ls_g[k*64 + tid];
    #pragma unroll
    for (int off = 1; off < 64; off <<= 1) p += __shfl_xor(p, off);
    outlj[rowbase + tid] = LOGJ[tid] + p;
  }
}

extern "C" void kernel_launch(void* const* d_in, const int* in_sizes, int n_in,
                              void* d_out, int out_size, void* d_ws, size_t ws_size,
                              hipStream_t stream)
{
  const float* q    = (const float*)d_in[0];
  const float* Hg   = (const float*)d_in[1];
  const int*   perms= (const int*)  d_in[2];
  const float* ls   = (const float*)d_in[3];
  const float* bi   = (const float*)d_in[4];
  const float* s1W1 = (const float*)d_in[5];
  const float* s1b1 = (const float*)d_in[6];
  const float* s1W2 = (const float*)d_in[7];
  const float* s1b2 = (const float*)d_in[8];
  const float* s2W1 = (const float*)d_in[9];
  const float* s2b1 = (const float*)d_in[10];
  const float* s2W2 = (const float*)d_in[11];
  const float* s2b2 = (const float*)d_in[12];
  float* outz  = (float*)d_out;
  float* outlj = outz + (size_t)B_ROWS * 64;

  unsigned short* wbf = (unsigned short*)d_ws;
  cvtw_frag<<<2688, 1024, 0, stream>>>(s1W1, s1W2, s2W1, s2W2, wbf);
  cinn_dma<<<512, 256, 0, stream>>>(q, Hg, perms, ls, bi,
                                    s1b1, s1b2, s2b1, s2b2,
                                    wbf, outz, outlj);
}